// Round 1
// baseline (207.192 us; speedup 1.0000x reference)
//
#include <hip/hip_runtime.h>

#define LAMBDA_COORD 5.0f
#define LAMBDA_NOOBJ 0.5f
#define DD 30
#define BLOCK 256
#define CPB 256                      // cells per block
#define CHUNKS ((CPB * DD * 4) / 1024)   // 30 x 1024B wave-chunks per input

// element k of a float2[15] register array (k compile-time after unroll)
#define EL(A, k) (((k) & 1) ? A[(k) >> 1].y : A[(k) >> 1].x)

__device__ __forceinline__ float iou_t(float tx, float ty, float tw, float th,
                                       float px, float py, float pw, float ph) {
    float xl = fmaxf(tx - tw * 0.5f, px - pw * 0.5f);
    float yt = fmaxf(ty - th * 0.5f, py - ph * 0.5f);
    float xr = fminf(tx + tw * 0.5f, px + pw * 0.5f);
    float yb = fminf(ty + th * 0.5f, py + ph * 0.5f);
    bool valid = (xr >= xl) && (yb >= yt);
    float inter = (xr - xl) * (yb - yt);
    float uni = tw * th + pw * ph - inter;
    float safe = (uni == 0.0f) ? 1.0f : uni;
    return valid ? (inter / safe) : 0.0f;
}

__global__ __launch_bounds__(BLOCK, 2) void yolo_loss_kernel(
    const float* __restrict__ pred, const float* __restrict__ targ,
    float* __restrict__ out) {
    // 2 x 30720 B staged tiles: 61.4 KB -> 2 blocks/CU (8 waves/CU)
    __shared__ __align__(16) float ldsP[CPB * DD];
    __shared__ __align__(16) float ldsT[CPB * DD];
    __shared__ float wpart[BLOCK / 64];

    const int tid  = threadIdx.x;
    const int lane = tid & 63;
    const int wv   = tid >> 6;

    const size_t base = (size_t)blockIdx.x * (CPB * DD);  // float index
    const float* gp = pred + base;
    const float* gt = targ + base;

    // ---- coalesced async global->LDS staging ----
    // one call = 64 lanes x 16 B = 1024 B contiguous; LDS dest is wave-uniform
    // base + lane*16 (linear), so global src is linear too.
    for (int s = wv; s < CHUNKS; s += BLOCK / 64) {
        __builtin_amdgcn_global_load_lds(
            (const __attribute__((address_space(1))) void*)(gp + s * 256 + lane * 4),
            (__attribute__((address_space(3))) void*)(ldsP + s * 256), 16, 0, 0);
        __builtin_amdgcn_global_load_lds(
            (const __attribute__((address_space(1))) void*)(gt + s * 256 + lane * 4),
            (__attribute__((address_space(3))) void*)(ldsT + s * 256), 16, 0, 0);
    }
    __syncthreads();  // compiler emits s_waitcnt vmcnt(0) before s_barrier

    // ---- per-cell loss, fragments read from LDS (float2 = ds_read_b64) ----
    const float2* lp = (const float2*)ldsP + tid * (DD / 2);
    const float2* lt = (const float2*)ldsT + tid * (DD / 2);

    float2 P[15], T[15];
#pragma unroll
    for (int j = 0; j < 15; ++j) P[j] = lp[j];
#pragma unroll
    for (int j = 0; j < 15; ++j) {
        if (j == 3 || j == 4) continue;  // target floats 6..9 are never used
        T[j] = lt[j];
    }

    float t4 = EL(T, 4);
    float obj = (t4 > 0.0f) ? 1.0f : 0.0f;
    float noobj = (t4 == 0.0f) ? 1.0f : 0.0f;

    float cls = 0.0f;
#pragma unroll
    for (int j = 5; j < 15; ++j) {   // channels 10..29
        float dx = T[j].x - P[j].x;
        float dy = T[j].y - P[j].y;
        cls += dx * dx + dy * dy;
    }
    cls *= obj;

    float d4 = t4 - EL(P, 4);
    float conf_noobj = noobj * d4 * d4;

    float tx = EL(T, 0), ty = EL(T, 1), tw = EL(T, 2), th = EL(T, 3);
    float p0 = EL(P, 0), p1 = EL(P, 1), p2 = EL(P, 2), p3 = EL(P, 3);
    float p4 = EL(P, 4), p5 = EL(P, 5), p6 = EL(P, 6), p7 = EL(P, 7);
    float p8 = EL(P, 8), p9 = EL(P, 9);

    float iou1 = iou_t(tx, ty, tw, th, p0, p1, p2, p3);
    float iou2 = iou_t(tx, ty, tw, th, p5, p6, p7, p8);
    float resp1 = (iou1 > iou2) ? 1.0f : 0.0f;
    float m1 = obj * resp1;
    float m2 = obj * (1.0f - resp1);

    float e1 = iou1 - p4;
    float e2 = iou2 - p9;
    float conf_obj = m1 * e1 * e1 + m2 * e2 * e2;

    float dx1 = tx - p0, dy1 = ty - p1;
    float dx2 = tx - p5, dy2 = ty - p6;
    float xy = m1 * (dx1 * dx1 + dy1 * dy1) + m2 * (dx2 * dx2 + dy2 * dy2);

    float dw1 = tw - p2, dh1 = th - p3;
    float dw2 = tw - p7, dh2 = th - p8;
    float wh = m1 * (dw1 * dw1 + dh1 * dh1) + m2 * (dw2 * dw2 + dh2 * dh2);

    float loss = LAMBDA_COORD * (xy + wh) + conf_obj + LAMBDA_NOOBJ * conf_noobj + cls;

    // ---- 64-lane wave reduction, then block reduction, one atomic/block ----
#pragma unroll
    for (int off = 32; off > 0; off >>= 1) loss += __shfl_down(loss, off);
    if ((tid & 63) == 0) wpart[tid >> 6] = loss;
    __syncthreads();
    if (tid == 0) {
        float s = wpart[0] + wpart[1] + wpart[2] + wpart[3];
        atomicAdd(out, s * (1.0f / 16384.0f));
    }
}

extern "C" void kernel_launch(void* const* d_in, const int* in_sizes, int n_in,
                              void* d_out, int out_size, void* d_ws, size_t ws_size,
                              hipStream_t stream) {
    const float* pred = (const float*)d_in[0];  // y
    const float* targ = (const float*)d_in[1];  // gt
    float* out = (float*)d_out;

    hipMemsetAsync(out, 0, sizeof(float), stream);

    const int cells = in_sizes[0] / DD;   // 802816
    const int grid = cells / CPB;         // 3136 (exact)
    yolo_loss_kernel<<<grid, BLOCK, 0, stream>>>(pred, targ, out);
}

// Round 3
// 206.438 us; speedup vs baseline: 1.0037x; 1.0037x over previous
//
#include <hip/hip_runtime.h>

#define LAMBDA_COORD 5.0f
#define LAMBDA_NOOBJ 0.5f
#define DD 30
#define BLOCK 128                 // 2 waves
#define CPB 128                   // cells per tile
#define TILE_FLOATS (CPB * DD)    // 3840 floats = 15360 B per input
#define GRID 512                  // persistent blocks, 2 per CU

// element k of a float2[15] register array (k compile-time after unroll)
#define EL(A, k) (((k) & 1) ? A[(k) >> 1].y : A[(k) >> 1].x)

__device__ __forceinline__ float iou_t(float tx, float ty, float tw, float th,
                                       float px, float py, float pw, float ph) {
    float xl = fmaxf(tx - tw * 0.5f, px - pw * 0.5f);
    float yt = fmaxf(ty - th * 0.5f, py - ph * 0.5f);
    float xr = fminf(tx + tw * 0.5f, px + pw * 0.5f);
    float yb = fminf(ty + th * 0.5f, py + ph * 0.5f);
    bool valid = (xr >= xl) && (yb >= yt);
    float inter = (xr - xl) * (yb - yt);
    float uni = tw * th + pw * ph - inter;
    float safe = (uni == 0.0f) ? 1.0f : uni;
    return valid ? (inter / safe) : 0.0f;
}

// Stage one 128-cell tile (P half by wave 0, T half by wave 1): 15 x 1024B
// coalesced async chunks per wave. LDS dest is wave-uniform base (+lane*16 HW).
__device__ __forceinline__ void stage_tile(const float* __restrict__ pred,
                                           const float* __restrict__ targ,
                                           size_t tile, float* buf,
                                           int wv, int lane) {
    const float* src = (wv ? targ : pred) + tile * (size_t)TILE_FLOATS + lane * 4;
    float* dst = buf + wv * TILE_FLOATS;
#pragma unroll
    for (int c = 0; c < 15; ++c) {
        __builtin_amdgcn_global_load_lds(
            (const __attribute__((address_space(1))) void*)(src + c * 256),
            (__attribute__((address_space(3))) void*)(dst + c * 256), 16, 0, 0);
    }
}

#define WAIT_VM15() asm volatile("s_waitcnt vmcnt(15)" ::: "memory")
#define WAIT_VM0()  asm volatile("s_waitcnt vmcnt(0)"  ::: "memory")

__global__ __launch_bounds__(BLOCK, 1) void yolo_loss_kernel(
    const float* __restrict__ pred, const float* __restrict__ targ,
    float* __restrict__ out, int n_tiles) {
    // double-buffered tile: 2 x (P 15360B + T 15360B) = 61440 B -> 2 blocks/CU
    __shared__ __align__(16) float lds[2][2 * TILE_FLOATS];
    __shared__ float wpart[BLOCK / 64];

    const int tid  = threadIdx.x;
    const int lane = tid & 63;
    const int wv   = tid >> 6;
    const int b    = blockIdx.x;

    const int my_tiles = (n_tiles - b + GRID - 1) / GRID;  // 12 or 13

    // ---- prologue: fill both buffers (each wave: 15 + 15 loads in flight) ----
    stage_tile(pred, targ, (size_t)b, lds[0], wv, lane);
    if (my_tiles > 1)
        stage_tile(pred, targ, (size_t)b + GRID, lds[1], wv, lane);

    float acc = 0.0f;

    for (int k = 0; k < my_tiles; ++k) {
        // wait for tile k's 15 loads (oldest); leave tile k+1's 15 in flight
        if (k + 1 < my_tiles) { WAIT_VM15(); } else { WAIT_VM0(); }
        __builtin_amdgcn_s_barrier();          // all waves: buf[k&1] complete
        __builtin_amdgcn_sched_barrier(0);

        const float* bufP = lds[k & 1];
        const float* bufT = lds[k & 1] + TILE_FLOATS;
        const float2* lp = (const float2*)bufP + tid * (DD / 2);
        const float2* lt = (const float2*)bufT + tid * (DD / 2);

        float2 P[15], T[15];
#pragma unroll
        for (int j = 0; j < 15; ++j) P[j] = lp[j];
#pragma unroll
        for (int j = 0; j < 15; ++j) {
            if (j == 3 || j == 4) continue;    // target floats 6..9 unused
            T[j] = lt[j];
        }

        float t4 = EL(T, 4);
        float obj = (t4 > 0.0f) ? 1.0f : 0.0f;
        float noobj = (t4 == 0.0f) ? 1.0f : 0.0f;

        float cls = 0.0f;
#pragma unroll
        for (int j = 5; j < 15; ++j) {         // channels 10..29
            float dx = T[j].x - P[j].x;
            float dy = T[j].y - P[j].y;
            cls += dx * dx + dy * dy;
        }
        cls *= obj;

        float d4 = t4 - EL(P, 4);
        float conf_noobj = noobj * d4 * d4;

        float tx = EL(T, 0), ty = EL(T, 1), tw = EL(T, 2), th = EL(T, 3);
        float p0 = EL(P, 0), p1 = EL(P, 1), p2 = EL(P, 2), p3 = EL(P, 3);
        float p4 = EL(P, 4), p5 = EL(P, 5), p6 = EL(P, 6), p7 = EL(P, 7);
        float p8 = EL(P, 8), p9 = EL(P, 9);

        float iou1 = iou_t(tx, ty, tw, th, p0, p1, p2, p3);
        float iou2 = iou_t(tx, ty, tw, th, p5, p6, p7, p8);
        float resp1 = (iou1 > iou2) ? 1.0f : 0.0f;
        float m1 = obj * resp1;
        float m2 = obj * (1.0f - resp1);

        float e1 = iou1 - p4;
        float e2 = iou2 - p9;
        float conf_obj = m1 * e1 * e1 + m2 * e2 * e2;

        float dx1 = tx - p0, dy1 = ty - p1;
        float dx2 = tx - p5, dy2 = ty - p6;
        float xy = m1 * (dx1 * dx1 + dy1 * dy1) + m2 * (dx2 * dx2 + dy2 * dy2);

        float dw1 = tw - p2, dh1 = th - p3;
        float dw2 = tw - p7, dh2 = th - p8;
        float wh = m1 * (dw1 * dw1 + dh1 * dh1) + m2 * (dw2 * dw2 + dh2 * dh2);

        acc += LAMBDA_COORD * (xy + wh) + conf_obj + LAMBDA_NOOBJ * conf_noobj + cls;

        __builtin_amdgcn_s_barrier();          // all waves done reading buf[k&1]
        __builtin_amdgcn_sched_barrier(0);

        if (k + 2 < my_tiles)                  // refill freed buffer, no wait
            stage_tile(pred, targ, (size_t)b + (size_t)(k + 2) * GRID,
                       lds[k & 1], wv, lane);
    }

    // ---- 64-lane wave reduction, then block reduction, one atomic/block ----
#pragma unroll
    for (int off = 32; off > 0; off >>= 1) acc += __shfl_down(acc, off);
    if (lane == 0) wpart[wv] = acc;
    __syncthreads();
    if (tid == 0) {
        atomicAdd(out, (wpart[0] + wpart[1]) * (1.0f / 16384.0f));
    }
}

extern "C" void kernel_launch(void* const* d_in, const int* in_sizes, int n_in,
                              void* d_out, int out_size, void* d_ws, size_t ws_size,
                              hipStream_t stream) {
    const float* pred = (const float*)d_in[0];  // y
    const float* targ = (const float*)d_in[1];  // gt
    float* out = (float*)d_out;

    hipMemsetAsync(out, 0, sizeof(float), stream);

    const int cells = in_sizes[0] / DD;     // 802816
    const int n_tiles = cells / CPB;        // 6272 (exact)
    yolo_loss_kernel<<<GRID, BLOCK, 0, stream>>>(pred, targ, out, n_tiles);
}